// Round 11
// baseline (224.145 us; speedup 1.0000x reference)
//
#include <hip/hip_runtime.h>

// out[b,o] = sum_e ( relu(relu(x[b,e,:]@W1[e]+b1[e])@W2[e]+b2[e]) @ W3[e] + b3[e] )
// E=16, DIN=128, H=512, DOUT=64, B=8192.  94.5 GFLOP.
//
// R17 = R16 fragment-packed weights (111us, MfmaUtil 35) + R15 16-wave structure.
// Diagnosis: R16's pipes run SERIALLY (MFMA 45us + LDS 46us + VALU 22us = 113
// ~ 111 measured) - the 2-waves/SIMD lockstep signature. R15 (4 waves/SIMD) was
// null ONLY because the then-bottleneck (weight gather, per-CU-bandwidth) was
// wave-invariant; that's fixed. Now stagger 4 waves/SIMD inside each phase so
// wave B's ds_reads run under wave A's MFMAs -> target max(LDS,MFMA) not sum.
//  - 1024-thread / 16-wave block, launch_bounds(1024,1); per-wave L1/L2 tile
//    64x32 (acc 32 AGPR), afr single-buffered, bfr 2-slot -> ~90 regs peak.
//  - L3: (2mp x 4n3 x 2kh) K-split, b3f[4] rotating; kh=1 skips bias.
//  - Packed bases for 32-col tiles: b1p/b2p = Wf+(e*8+(w>>1))*{8192,32768}
//    +(w&1)*1024+lane*8, frag(kt,n)=+kt*2048+n*512; b3p=W3f+(e*4+n3)*8192.
//  - Same bytes/math as R16 -> absmax must stay EXACTLY 0.0078125 (canary).
// Kept: dual-sH 2-barrier skeleton, EG=4, swapped-operand b64 epilogue,
//   bias-in-acc, XCD expert pinning, folded memset, R16 prep verbatim.

#define NE   16
#define NDIN 128
#define NH   512
#define NDO  64
#define NB   8192
#define EG   4

using bf16x8 = __attribute__((ext_vector_type(8))) __bf16;
using bf16x4 = __attribute__((ext_vector_type(4))) __bf16;
using f32x4  = __attribute__((ext_vector_type(4))) float;

__device__ __forceinline__ unsigned short f2bf(float f) {
    union { float f; unsigned u; } v; v.f = f;
    unsigned r = v.u + 0x7FFFu + ((v.u >> 16) & 1u);   // RNE
    return (unsigned short)(r >> 16);
}

// compiler-fusable bf16 conversion (emits v_cvt_pk_bf16_f32 pairs)
__device__ __forceinline__ bf16x8 cvt8(float4 a, float4 b) {
    bf16x8 r;
    r[0] = (__bf16)a.x; r[1] = (__bf16)a.y; r[2] = (__bf16)a.z; r[3] = (__bf16)a.w;
    r[4] = (__bf16)b.x; r[5] = (__bf16)b.y; r[6] = (__bf16)b.z; r[7] = (__bf16)b.w;
    return r;
}

// Swizzled index (ushort units): 16B granules XOR'd by row&15 (0 conflicts measured).
__device__ __forceinline__ int shidx(int m, int n) {          // H tile, stride 512
    return m * NH + (((n >> 3) ^ (m & 15)) << 3) + (n & 7);
}
__device__ __forceinline__ int shx(int m, int n) {            // X tile, stride 128
    return m * NDIN + ((((n >> 3) ^ (m & 15)) & 15) << 3) + (n & 7);
}

// ---------------- prep: fp32 weights -> bf16 FRAGMENT-PACKED (+ out zeroing) ----------------
// value(e,t,kt,lane=q*16+l16,j) = Wsrc[e][kt*32 + q*8 + j][t*16 + l16]
// W1/W2 chunk offset: (((e*8 + t>>2)*NKT + kt)*4 + (t&3))*512 + lane*8
// W3   chunk offset: ((e*4 + t)*16 + kt)*512 + lane*8
__global__ __launch_bounds__(256) void prep_weights(
    const float* __restrict__ W1, const float* __restrict__ W2, const float* __restrict__ W3,
    unsigned short* __restrict__ W1f, unsigned short* __restrict__ W2f, unsigned short* __restrict__ W3f,
    float* __restrict__ out)
{
    __shared__ float lds[32][521];   // 521 pad -> 2-way max on frag gather (free)
    const int job = blockIdx.x, tt = threadIdx.x;
    // fold the output memset: first 64 jobs clear 32KB each (2MB total)
    if (job < 64) {
        float4* oz = (float4*)(out + (size_t)job * 8192);
        const float4 z = {0.f, 0.f, 0.f, 0.f};
#pragma unroll
        for (int i = 0; i < 8; ++i) oz[i * 256 + tt] = z;
    }
    const float* src; unsigned short* dst; int e, kt, C, NKT, isW3;
    if (job < 64)       { e = job >> 2;                kt = job & 3;  src = W1; dst = W1f; C = NH;  NKT = 4;  isW3 = 0; }
    else if (job < 320) { int q = job - 64;  e = q >> 4; kt = q & 15; src = W2; dst = W2f; C = NH;  NKT = 16; isW3 = 0; }
    else                { int q = job - 320; e = q >> 4; kt = q & 15; src = W3; dst = W3f; C = NDO; NKT = 16; isW3 = 1; }

    // stage the 32 x C slab (k-rows kt*32..+31 of src[e])
    const float* s = src + ((size_t)e * (NKT * 32) + kt * 32) * C;
    const int nf4 = (32 * C) >> 2;
    for (int i = tt; i < nf4; i += 256) {
        const int r = i / (C >> 2), c4 = (i % (C >> 2)) * 4;
        const float4 v = *(const float4*)(s + (size_t)r * C + c4);
        lds[r][c4 + 0] = v.x; lds[r][c4 + 1] = v.y;
        lds[r][c4 + 2] = v.z; lds[r][c4 + 3] = v.w;
    }
    __syncthreads();

    // emit 1KB fragment chunks, coalesced (consecutive lanes -> consecutive 16B)
    const int npair = (C >> 4) * 64;
    for (int p = tt; p < npair; p += 256) {
        const int t = p >> 6, lane = p & 63, q = lane >> 4, l16 = lane & 15;
        union { unsigned short u[8]; uint4 v; } pk;
#pragma unroll
        for (int j = 0; j < 8; ++j) pk.u[j] = f2bf(lds[q * 8 + j][t * 16 + l16]);
        size_t off;
        if (isW3) off = (((size_t)e * 4 + t) * 16 + kt) * 512 + lane * 8;
        else      off = ((((size_t)e * 8 + (t >> 2)) * NKT + kt) * 4 + (t & 3)) * 512 + lane * 8;
        *(uint4*)(dst + off) = pk.v;
    }
}

// ---------------- fused 3-layer expert MLP: 4 experts x 64 rows per 16-wave WG ----------------
__global__ __launch_bounds__(1024, 1) void moe_fused(
    const float* __restrict__ x,            // [B][E][DIN]
    const float* __restrict__ b1,           // [E][H]
    const float* __restrict__ b2,           // [E][H]
    const float* __restrict__ b3,           // [E][DOUT]
    const unsigned short* __restrict__ W1f, // fragment-packed
    const unsigned short* __restrict__ W2f,
    const unsigned short* __restrict__ W3f,
    float* __restrict__ out)                // [B][DOUT]  (pre-zeroed by prep)
{
    __shared__ unsigned short sMem[64 * NDIN + 2 * 64 * NH];  // 16KB X + 2x64KB H = 144KB
    unsigned short* sX  = sMem;
    unsigned short* sHA = sMem + 64 * NDIN;            // L1 output (read by L2)
    unsigned short* sHB = sHA + 64 * NH;               // L2 output (read by L3)

    const int tid  = threadIdx.x;
    const int wave = tid >> 6;            // 0..15
    const int lane = tid & 63;
    const int q    = lane >> 4;
    const int l16  = lane & 15;
    const int hi2  = l16 >> 2;
    const int lo2  = l16 & 3;
    const int qe   = (q ^ lo2) * 8;       // swizzled in-granule element offset

    // grid 512: xcd = lin&7; e-group = xcd>>1 (4 experts pinned per XCD pair);
    // row-tile = ((lin>>3)<<1)|(xcd&1) in 0..127.
    const int lin = blockIdx.x;
    const int xcd = lin & 7;
    const int eg  = xcd >> 1;
    const int rt  = ((lin >> 3) << 1) | (xcd & 1);
    const int b0  = rt << 6;
    const int nb  = wave * 32;            // 32 H-cols per wave in L1/L2

    // per-wave LDS A-frag base offsets (elements);  read addr = base + ((kt^hi2)<<5)
    int aH[4], aX[4];
#pragma unroll
    for (int m = 0; m < 4; ++m) {
        aH[m] = (m * 16 + l16) * NH   + qe;
        aX[m] = (m * 16 + l16) * NDIN + qe;
    }
    const int r0 = tid >> 4, c8 = (tid & 15) * 8;   // x staging coords (1024 thr = 64x16)

    // L3 wave mapping: (2 mp) x (4 n3) x (2 kh K-halves)
    const int n3 = wave & 3, mp = (wave >> 2) & 1, kh = wave >> 3;
    int a3[2];
#pragma unroll
    for (int i = 0; i < 2; ++i) a3[i] = ((2 * mp + i) * 16 + l16) * NH + qe;

    f32x4 oacc[2];
    oacc[0] = {0.f, 0.f, 0.f, 0.f}; oacc[1] = {0.f, 0.f, 0.f, 0.f};
    float bacc = 0.f;

    bf16x8 afr[4];      // A-frags, SINGLE-buffered (4-wave TLP covers latency)
    bf16x8 bfr[2][2];   // weight B-frags, 2-slot

    // fragment-packed per-wave sub-bases (expert-invariant parts)
    const size_t wb12 = (size_t)(wave >> 1);
    const size_t wlo  = (size_t)(wave & 1) * 1024 + lane * 8;

    // ---- prologue: stage sX(e0): one bf16x8 per thread ----
    {
        const int e0 = eg * EG;
        const float* p = x + ((size_t)(b0 + r0) * NE + e0) * NDIN + c8;
        float4 u0 = *(const float4*)p, u1 = *(const float4*)(p + 4);
        *(bf16x8*)&sX[shx(r0, c8)] = cvt8(u0, u1);
    }
    __syncthreads();   // BAR-0: sX(e0) visible

#pragma unroll 1
    for (int ei = 0; ei < EG; ++ei) {
        const int e = eg * EG + ei;

        // packed weight bases for this expert
        const unsigned short* b1p = W1f + ((size_t)e * 8 + wb12) * 8192  + wlo;
        const unsigned short* b2p = W2f + ((size_t)e * 8 + wb12) * 32768 + wlo;

        // W1 kt=0 frags + b1 at iter top
#pragma unroll
        for (int n = 0; n < 2; ++n)
            bfr[0][n] = *(const bf16x8*)(b1p + n * 512);
        float4 b1q[2];
#pragma unroll
        for (int n = 0; n < 2; ++n)
            b1q[n] = *(const float4*)(b1 + e * NH + nb + n * 16 + q * 4);

        // ---------------- layer 1: acc = X @ W1 + b1, 4 kt ----------------
        f32x4 acc[4][2];
#pragma unroll
        for (int n = 0; n < 2; ++n) {
            const f32x4 bi = {b1q[n].x, b1q[n].y, b1q[n].z, b1q[n].w};
#pragma unroll
            for (int m = 0; m < 4; ++m) acc[m][n] = bi;
        }

#pragma unroll
        for (int kt = 0; kt < 4; ++kt) {
            if (kt < 3)
#pragma unroll
                for (int n = 0; n < 2; ++n)
                    bfr[(kt + 1) & 1][n] = *(const bf16x8*)(b1p + (kt + 1) * 2048 + n * 512);
#pragma unroll
            for (int m = 0; m < 4; ++m)
                afr[m] = *(const bf16x8*)&sX[aX[m] + (((kt ^ hi2) & 3) << 5)];
#pragma unroll
            for (int m = 0; m < 4; ++m)
#pragma unroll
                for (int n = 0; n < 2; ++n)
                    acc[m][n] = __builtin_amdgcn_mfma_f32_16x16x32_bf16(
                        bfr[kt & 1][n], afr[m], acc[m][n], 0, 0, 0);
        }

        // W2 kt=0 prologue + b2 in flight over the H1 epilogue + barrier
#pragma unroll
        for (int n = 0; n < 2; ++n)
            bfr[0][n] = *(const bf16x8*)(b2p + n * 512);
        float4 b2q[2];
#pragma unroll
        for (int n = 0; n < 2; ++n)
            b2q[n] = *(const float4*)(b2 + e * NH + nb + n * 16 + q * 4);

        // H1 epilogue -> sHA (WAR-safe: L2(e-1) readers ended before BAR-2(e-1))
#pragma unroll
        for (int n = 0; n < 2; ++n) {
            const int c0 = nb + n * 16 + q * 4;
#pragma unroll
            for (int m = 0; m < 4; ++m) {
                bf16x4 pk;
#pragma unroll
                for (int r = 0; r < 4; ++r) pk[r] = (__bf16)fmaxf(acc[m][n][r], 0.f);
                *(bf16x4*)&sHA[shidx(m * 16 + l16, c0)] = pk;
            }
        }
        __syncthreads();   // BAR-1: sHA visible (also orders L3(e-1) before H2epi below)

        // ---------------- layer 2: acc2 = H1 @ W2 (+b2), 16 kt ----------------
        f32x4 acc2[4][2];
#pragma unroll
        for (int n = 0; n < 2; ++n) {
            const f32x4 bi = {b2q[n].x, b2q[n].y, b2q[n].z, b2q[n].w};
#pragma unroll
            for (int m = 0; m < 4; ++m) acc2[m][n] = bi;
        }

#pragma unroll
        for (int kt = 0; kt < 16; ++kt) {
            if (kt < 15)
#pragma unroll
                for (int n = 0; n < 2; ++n)
                    bfr[(kt + 1) & 1][n] = *(const bf16x8*)(b2p + (kt + 1) * 2048 + n * 512);
#pragma unroll
            for (int m = 0; m < 4; ++m)
                afr[m] = *(const bf16x8*)&sHA[aH[m] + (((kt ^ hi2)) << 5)];
#pragma unroll
            for (int m = 0; m < 4; ++m)
#pragma unroll
                for (int n = 0; n < 2; ++n)
                    acc2[m][n] = __builtin_amdgcn_mfma_f32_16x16x32_bf16(
                        bfr[kt & 1][n], afr[m], acc2[m][n], 0, 0, 0);
        }

        // W3 kh-half b3f preload (3 of 4 slots) + b3 + X(e+1) prefetch (8 regs)
        const unsigned short* b3p = W3f + ((size_t)e * 4 + n3) * 8192 + lane * 8;
        bf16x8 b3f[4];
#pragma unroll
        for (int j = 0; j < 3; ++j) b3f[j] = *(const bf16x8*)(b3p + (kh * 8 + j) * 512);
        const float b3v = b3[e * NDO + n3 * 16 + l16];

        float4 xu0, xu1;
        {
            const int en = eg * EG + ((ei + 1) & (EG - 1));   // wrap: ei=3 redundant, harmless
            const float* p = x + ((size_t)(b0 + r0) * NE + en) * NDIN + c8;
            xu0 = *(const float4*)p; xu1 = *(const float4*)(p + 4);
        }

        // H2 epilogue -> sHB (WAR-safe: L3(e-1) readers ended before BAR-1(e))
#pragma unroll
        for (int n = 0; n < 2; ++n) {
            const int c0 = nb + n * 16 + q * 4;
#pragma unroll
            for (int m = 0; m < 4; ++m) {
                bf16x4 pk;
#pragma unroll
                for (int r = 0; r < 4; ++r) pk[r] = (__bf16)fmaxf(acc2[m][n][r], 0.f);
                *(bf16x4*)&sHB[shidx(m * 16 + l16, c0)] = pk;
            }
        }
        // stage sX(e+1) (WAR-safe: L1(e) readers ended before BAR-1(e))
        *(bf16x8*)&sX[shx(r0, c8)] = cvt8(xu0, xu1);
        __syncthreads();   // BAR-2: sHB + sX(e+1) visible

        // ---------------- layer 3: oacc += H2[kh-half] @ W3 ----------------
        bf16x8 a3f[2][2];
#pragma unroll
        for (int i = 0; i < 2; ++i)
            a3f[0][i] = *(const bf16x8*)&sHB[a3[i] + ((((kh * 8) ^ hi2)) << 5)];

#pragma unroll
        for (int j = 0; j < 8; ++j) {
            const int kt = kh * 8 + j;
            if (j < 7)
#pragma unroll
                for (int i = 0; i < 2; ++i)
                    a3f[(j + 1) & 1][i] = *(const bf16x8*)&sHB[a3[i] + ((((kt + 1) ^ hi2)) << 5)];
            if (j < 5)
                b3f[(j + 3) & 3] = *(const bf16x8*)(b3p + (kh * 8 + j + 3) * 512);
#pragma unroll
            for (int i = 0; i < 2; ++i)
                oacc[i] = __builtin_amdgcn_mfma_f32_16x16x32_bf16(
                    a3f[j & 1][i], b3f[j & 3], oacc[i], 0, 0, 0);
        }
        bacc += kh ? 0.f : b3v;   // bias only from the kh=0 half (no double-count)
    }

    // final: 4-expert-accumulated contribution -> global fp32 atomics
#pragma unroll
    for (int i = 0; i < 2; ++i) {
        const int col = n3 * 16 + l16;
#pragma unroll
        for (int r = 0; r < 4; ++r) {
            const int row = b0 + (2 * mp + i) * 16 + q * 4 + r;
            unsafeAtomicAdd(out + (size_t)row * NDO + col, oacc[i][r] + bacc);
        }
    }
}

extern "C" void kernel_launch(void* const* d_in, const int* in_sizes, int n_in,
                              void* d_out, int out_size, void* d_ws, size_t ws_size,
                              hipStream_t stream) {
    const float* x  = (const float*)d_in[0];
    const float* W1 = (const float*)d_in[1];
    const float* b1 = (const float*)d_in[2];
    const float* W2 = (const float*)d_in[3];
    const float* b2 = (const float*)d_in[4];
    const float* W3 = (const float*)d_in[5];
    const float* b3 = (const float*)d_in[6];
    float* out = (float*)d_out;

    unsigned short* W1f = (unsigned short*)d_ws;            // [E*8][4][4][64][8]
    unsigned short* W2f = W1f + (size_t)NE * NH * NDIN;     // [E*8][16][4][64][8]
    unsigned short* W3f = W2f + (size_t)NE * NH * NH;       // [E*4][16][64][8]

    prep_weights<<<dim3(576), 256, 0, stream>>>(W1, W2, W3, W1f, W2f, W3f, out);
    moe_fused<<<dim3((NB / 64) * (NE / EG)), 1024, 0, stream>>>(x, b1, b2, b3, W1f, W2f, W3f, out);
}

// Round 12
// 212.066 us; speedup vs baseline: 1.0570x; 1.0570x over previous
//
#include <hip/hip_runtime.h>

// out[b,o] = sum_e ( relu(relu(x[b,e,:]@W1[e]+b1[e])@W2[e]+b2[e]) @ W3[e] + b3[e] )
// E=16, DIN=128, H=512, DOUT=64, B=8192.  94.5 GFLOP.
//
// R18 = R16 (fragment-packed, 111us, MfmaUtil 35) + latency-cover changes.
// R17 lesson: 1024-thr blocks always get VGPR capped at 64 -> spill (3rd time).
// 512-thr / 2 waves/SIMD is the regime; attack latency exposure inside it:
//  (1) bfr 4-slot lookahead-3 in L2 (~240cy cover vs ~200-300cy L2-hit latency;
//      old lookahead-2 ~160cy stalled every kt). W2 prologue preloads kt0-2.
//  (2) cross-expert W1/b1 prefetch into the DEAD bfr slots after L2's last use;
//      carried through L3 + loop back-edge (BAR-2->L3->L1->BAR-1 is barrier-
//      free), removing serial W1 latency at each L1 start. Issue order:
//      b3f -> xu -> W1next so xu's waitcnt leaves W1next in flight.
//  (3) launch_bounds(512,1): the (512,2) bound caps arch VGPR at 128 (R14 hit
//      it + 1MB scratch). Peak live now ~160 arch + 64 AGPR = 224 < 256 ->
//      still 2 waves/SIMD, no forced spill.
// Same bytes/math as R16 -> absmax must stay EXACTLY 0.0078125 (canary).
// Kept: packed prep verbatim, dual-sH 2-barrier skeleton, EG=4, swapped-operand
//   b64 epilogue, bias-in-acc, XCD expert pinning, folded memset, no setprio.

#define NE   16
#define NDIN 128
#define NH   512
#define NDO  64
#define NB   8192
#define EG   4

using bf16x8 = __attribute__((ext_vector_type(8))) __bf16;
using bf16x4 = __attribute__((ext_vector_type(4))) __bf16;
using f32x4  = __attribute__((ext_vector_type(4))) float;

__device__ __forceinline__ unsigned short f2bf(float f) {
    union { float f; unsigned u; } v; v.f = f;
    unsigned r = v.u + 0x7FFFu + ((v.u >> 16) & 1u);   // RNE
    return (unsigned short)(r >> 16);
}

// compiler-fusable bf16 conversion (emits v_cvt_pk_bf16_f32 pairs)
__device__ __forceinline__ bf16x8 cvt8(float4 a, float4 b) {
    bf16x8 r;
    r[0] = (__bf16)a.x; r[1] = (__bf16)a.y; r[2] = (__bf16)a.z; r[3] = (__bf16)a.w;
    r[4] = (__bf16)b.x; r[5] = (__bf16)b.y; r[6] = (__bf16)b.z; r[7] = (__bf16)b.w;
    return r;
}

// Swizzled index (ushort units): 16B granules XOR'd by row&15 (0 conflicts measured).
__device__ __forceinline__ int shidx(int m, int n) {          // H tile, stride 512
    return m * NH + (((n >> 3) ^ (m & 15)) << 3) + (n & 7);
}
__device__ __forceinline__ int shx(int m, int n) {            // X tile, stride 128
    return m * NDIN + ((((n >> 3) ^ (m & 15)) & 15) << 3) + (n & 7);
}

// ---------------- prep: fp32 weights -> bf16 FRAGMENT-PACKED (+ out zeroing) ----------------
// value(e,t,kt,lane=q*16+l16,j) = Wsrc[e][kt*32 + q*8 + j][t*16 + l16]
// W1/W2 chunk offset: (((e*8 + t>>2)*NKT + kt)*4 + (t&3))*512 + lane*8
// W3   chunk offset: ((e*4 + t)*16 + kt)*512 + lane*8
__global__ __launch_bounds__(256) void prep_weights(
    const float* __restrict__ W1, const float* __restrict__ W2, const float* __restrict__ W3,
    unsigned short* __restrict__ W1f, unsigned short* __restrict__ W2f, unsigned short* __restrict__ W3f,
    float* __restrict__ out)
{
    __shared__ float lds[32][521];   // 521 pad -> 2-way max on frag gather (free)
    const int job = blockIdx.x, tt = threadIdx.x;
    // fold the output memset: first 64 jobs clear 32KB each (2MB total)
    if (job < 64) {
        float4* oz = (float4*)(out + (size_t)job * 8192);
        const float4 z = {0.f, 0.f, 0.f, 0.f};
#pragma unroll
        for (int i = 0; i < 8; ++i) oz[i * 256 + tt] = z;
    }
    const float* src; unsigned short* dst; int e, kt, C, NKT, isW3;
    if (job < 64)       { e = job >> 2;                kt = job & 3;  src = W1; dst = W1f; C = NH;  NKT = 4;  isW3 = 0; }
    else if (job < 320) { int q = job - 64;  e = q >> 4; kt = q & 15; src = W2; dst = W2f; C = NH;  NKT = 16; isW3 = 0; }
    else                { int q = job - 320; e = q >> 4; kt = q & 15; src = W3; dst = W3f; C = NDO; NKT = 16; isW3 = 1; }

    // stage the 32 x C slab (k-rows kt*32..+31 of src[e])
    const float* s = src + ((size_t)e * (NKT * 32) + kt * 32) * C;
    const int nf4 = (32 * C) >> 2;
    for (int i = tt; i < nf4; i += 256) {
        const int r = i / (C >> 2), c4 = (i % (C >> 2)) * 4;
        const float4 v = *(const float4*)(s + (size_t)r * C + c4);
        lds[r][c4 + 0] = v.x; lds[r][c4 + 1] = v.y;
        lds[r][c4 + 2] = v.z; lds[r][c4 + 3] = v.w;
    }
    __syncthreads();

    // emit 1KB fragment chunks, coalesced (consecutive lanes -> consecutive 16B)
    const int npair = (C >> 4) * 64;
    for (int p = tt; p < npair; p += 256) {
        const int t = p >> 6, lane = p & 63, q = lane >> 4, l16 = lane & 15;
        union { unsigned short u[8]; uint4 v; } pk;
#pragma unroll
        for (int j = 0; j < 8; ++j) pk.u[j] = f2bf(lds[q * 8 + j][t * 16 + l16]);
        size_t off;
        if (isW3) off = (((size_t)e * 4 + t) * 16 + kt) * 512 + lane * 8;
        else      off = ((((size_t)e * 8 + (t >> 2)) * NKT + kt) * 4 + (t & 3)) * 512 + lane * 8;
        *(uint4*)(dst + off) = pk.v;
    }
}

// ---------------- fused 3-layer expert MLP: 4 experts x 64 rows per WG ----------------
__global__ __launch_bounds__(512, 1) void moe_fused(
    const float* __restrict__ x,            // [B][E][DIN]
    const float* __restrict__ b1,           // [E][H]
    const float* __restrict__ b2,           // [E][H]
    const float* __restrict__ b3,           // [E][DOUT]
    const unsigned short* __restrict__ W1f, // fragment-packed
    const unsigned short* __restrict__ W2f,
    const unsigned short* __restrict__ W3f,
    float* __restrict__ out)                // [B][DOUT]  (pre-zeroed by prep)
{
    __shared__ unsigned short sMem[64 * NDIN + 2 * 64 * NH];  // 16KB X + 2x64KB H = 144KB
    unsigned short* sX  = sMem;
    unsigned short* sHA = sMem + 64 * NDIN;            // L1 output (read by L2)
    unsigned short* sHB = sHA + 64 * NH;               // L2 output (read by L3)

    const int tid  = threadIdx.x;
    const int wave = tid >> 6;
    const int lane = tid & 63;
    const int q    = lane >> 4;
    const int l16  = lane & 15;
    const int hi2  = l16 >> 2;
    const int lo2  = l16 & 3;
    const int qe   = (q ^ lo2) * 8;       // swizzled in-granule element offset

    // grid 512: xcd = lin&7; e-group = xcd>>1 (4 experts pinned per XCD pair);
    // row-tile = ((lin>>3)<<1)|(xcd&1) in 0..127.
    const int lin = blockIdx.x;
    const int xcd = lin & 7;
    const int eg  = xcd >> 1;
    const int rt  = ((lin >> 3) << 1) | (xcd & 1);
    const int b0  = rt << 6;

    // per-wave LDS A-frag base offsets (elements);  read addr = base + ((kt^hi2)<<5)
    int aH[4], aX[4];
#pragma unroll
    for (int m = 0; m < 4; ++m) {
        aH[m] = (m * 16 + l16) * NH   + qe;
        aX[m] = (m * 16 + l16) * NDIN + qe;
    }
    const int r0 = tid >> 4, c8 = (tid & 15) * 8;   // x staging coords

    // L3 wave mapping (constant across experts)
    const int n3 = wave & 3, mp = wave >> 2;
    int a3[2];
#pragma unroll
    for (int i = 0; i < 2; ++i) a3[i] = ((2 * mp + i) * 16 + l16) * NH + qe;

    bf16x8 bfr[4][4], afr[3][4];
    float4 b1q[4];

    f32x4 oacc[2];
    oacc[0] = {0.f, 0.f, 0.f, 0.f}; oacc[1] = {0.f, 0.f, 0.f, 0.f};
    float bacc = 0.f;

    // ---- prologue: stage sX(e0) + W1(e0) kt0-1 + b1(e0) ----
    {
        const int e0 = eg * EG;
        const float* p0 = x + ((size_t)(b0 + r0)      * NE + e0) * NDIN + c8;
        const float* p1 = x + ((size_t)(b0 + 32 + r0) * NE + e0) * NDIN + c8;
        float4 u0 = *(const float4*)p0, u1 = *(const float4*)(p0 + 4);
        float4 u2 = *(const float4*)p1, u3 = *(const float4*)(p1 + 4);
        *(bf16x8*)&sX[shx(r0, c8)]      = cvt8(u0, u1);
        *(bf16x8*)&sX[shx(32 + r0, c8)] = cvt8(u2, u3);
        const unsigned short* b1p0 = W1f + (size_t)e0 * NH * NDIN + wave * 8192 + lane * 8;
#pragma unroll
        for (int s = 0; s < 2; ++s)
#pragma unroll
            for (int n = 0; n < 4; ++n)
                bfr[s][n] = *(const bf16x8*)(b1p0 + s * 2048 + n * 512);
#pragma unroll
        for (int n = 0; n < 4; ++n)
            b1q[n] = *(const float4*)(b1 + e0 * NH + wave * 64 + n * 16 + q * 4);
    }
    __syncthreads();   // BAR-0: sX(e0) visible

#pragma unroll 1
    for (int ei = 0; ei < EG; ++ei) {
        const int e = eg * EG + ei;

        // fragment-packed weight bases (contiguous 4KB per kt across n)
        const unsigned short* b1p = W1f + (size_t)e * NH * NDIN + wave * 8192  + lane * 8;
        const unsigned short* b2p = W2f + (size_t)e * NH * NH   + wave * 32768 + lane * 8;

        // ---------------- layer 1: acc = X @ W1 + b1, 4 kt ----------------
        // (bfr[0..1] and b1q arrive prefetched: prologue for ei=0, L3-slot for ei>0)
        f32x4 acc[4][4];
#pragma unroll
        for (int n = 0; n < 4; ++n) {
            const f32x4 bi = {b1q[n].x, b1q[n].y, b1q[n].z, b1q[n].w};
#pragma unroll
            for (int m = 0; m < 4; ++m) acc[m][n] = bi;
        }
#pragma unroll
        for (int s = 0; s < 2; ++s)
#pragma unroll
            for (int m = 0; m < 4; ++m)
                afr[s][m] = *(const bf16x8*)&sX[aX[m] + (((s ^ hi2) & 3) << 5)];

#pragma unroll
        for (int kt = 0; kt < 4; ++kt) {
            if (kt < 2) {
#pragma unroll
                for (int n = 0; n < 4; ++n)
                    bfr[(kt + 2) & 3][n] = *(const bf16x8*)(b1p + (kt + 2) * 2048 + n * 512);
#pragma unroll
                for (int m = 0; m < 4; ++m)
                    afr[(kt + 2) % 3][m] = *(const bf16x8*)&sX[aX[m] + ((((kt + 2) ^ hi2) & 3) << 5)];
            }
#pragma unroll
            for (int m = 0; m < 4; ++m)
#pragma unroll
                for (int n = 0; n < 4; ++n)
                    acc[m][n] = __builtin_amdgcn_mfma_f32_16x16x32_bf16(
                        bfr[kt & 3][n], afr[kt % 3][m], acc[m][n], 0, 0, 0);
        }

        // W2 prologue (kt0-2, lookahead-3) + b2 in flight over the H1 epilogue + barrier
#pragma unroll
        for (int s = 0; s < 3; ++s)
#pragma unroll
            for (int n = 0; n < 4; ++n)
                bfr[s][n] = *(const bf16x8*)(b2p + s * 2048 + n * 512);
        float4 b2q[4];
#pragma unroll
        for (int n = 0; n < 4; ++n)
            b2q[n] = *(const float4*)(b2 + e * NH + wave * 64 + n * 16 + q * 4);

        // H1 epilogue -> sHA (WAR-safe: L2(e-1) readers ended before BAR-2(e-1))
#pragma unroll
        for (int n = 0; n < 4; ++n) {
            const int c0 = wave * 64 + n * 16 + q * 4;
#pragma unroll
            for (int m = 0; m < 4; ++m) {
                bf16x4 pk;
#pragma unroll
                for (int r = 0; r < 4; ++r) pk[r] = (__bf16)fmaxf(acc[m][n][r], 0.f);
                *(bf16x4*)&sHA[shidx(m * 16 + l16, c0)] = pk;
            }
        }
        __syncthreads();   // BAR-1: sHA visible (also orders L3(e-1) before H2epi below)

        // ---------------- layer 2: acc2 = H1 @ W2 (+b2), 16 kt, lookahead-3 ----------------
        f32x4 acc2[4][4];
#pragma unroll
        for (int n = 0; n < 4; ++n) {
            const f32x4 bi = {b2q[n].x, b2q[n].y, b2q[n].z, b2q[n].w};
#pragma unroll
            for (int m = 0; m < 4; ++m) acc2[m][n] = bi;
        }
#pragma unroll
        for (int s = 0; s < 2; ++s)
#pragma unroll
            for (int m = 0; m < 4; ++m)
                afr[s][m] = *(const bf16x8*)&sHA[aH[m] + (((s ^ hi2)) << 5)];

#pragma unroll
        for (int kt = 0; kt < 16; ++kt) {
            if (kt < 13)
#pragma unroll
                for (int n = 0; n < 4; ++n)
                    bfr[(kt + 3) & 3][n] = *(const bf16x8*)(b2p + (kt + 3) * 2048 + n * 512);
            if (kt < 14)
#pragma unroll
                for (int m = 0; m < 4; ++m)
                    afr[(kt + 2) % 3][m] = *(const bf16x8*)&sHA[aH[m] + ((((kt + 2) ^ hi2)) << 5)];
#pragma unroll
            for (int m = 0; m < 4; ++m)
#pragma unroll
                for (int n = 0; n < 4; ++n)
                    acc2[m][n] = __builtin_amdgcn_mfma_f32_16x16x32_bf16(
                        bfr[kt & 3][n], afr[kt % 3][m], acc2[m][n], 0, 0, 0);
        }

        // W3 first half + b3; X(e+1) -> regs; then W1(e+1)/b1(e+1) into dead bfr
        // slots (carried through L3 + back-edge; issue AFTER xu so xu's waitcnt
        // leaves them in flight).
        const unsigned short* b3p = W3f + ((size_t)e * 4 + n3) * 8192 + lane * 8;
        bf16x8 b3f[8];
#pragma unroll
        for (int j = 0; j < 8; ++j) b3f[j] = *(const bf16x8*)(b3p + j * 512);
        const float b3v = b3[e * NDO + n3 * 16 + l16];

        const int en = eg * EG + ((ei + 1) & (EG - 1));   // wrap: ei=3 redundant, harmless
        float4 xu0, xu1, xu2, xu3;
        {
            const float* pn0 = x + ((size_t)(b0 + r0)      * NE + en) * NDIN + c8;
            const float* pn1 = x + ((size_t)(b0 + 32 + r0) * NE + en) * NDIN + c8;
            xu0 = *(const float4*)pn0; xu1 = *(const float4*)(pn0 + 4);
            xu2 = *(const float4*)pn1; xu3 = *(const float4*)(pn1 + 4);
        }
        {
            const unsigned short* b1pn = W1f + (size_t)en * NH * NDIN + wave * 8192 + lane * 8;
#pragma unroll
            for (int s = 0; s < 2; ++s)
#pragma unroll
                for (int n = 0; n < 4; ++n)
                    bfr[s][n] = *(const bf16x8*)(b1pn + s * 2048 + n * 512);
#pragma unroll
            for (int n = 0; n < 4; ++n)
                b1q[n] = *(const float4*)(b1 + en * NH + wave * 64 + n * 16 + q * 4);
        }

        // H2 epilogue -> sHB (WAR-safe: L3(e-1) readers ended before BAR-1(e))
#pragma unroll
        for (int n = 0; n < 4; ++n) {
            const int c0 = wave * 64 + n * 16 + q * 4;
#pragma unroll
            for (int m = 0; m < 4; ++m) {
                bf16x4 pk;
#pragma unroll
                for (int r = 0; r < 4; ++r) pk[r] = (__bf16)fmaxf(acc2[m][n][r], 0.f);
                *(bf16x4*)&sHB[shidx(m * 16 + l16, c0)] = pk;
            }
        }
        // stage sX(e+1) (WAR-safe: L1(e) readers ended before BAR-1(e))
        *(bf16x8*)&sX[shx(r0, c8)]      = cvt8(xu0, xu1);
        *(bf16x8*)&sX[shx(32 + r0, c8)] = cvt8(xu2, xu3);
        __syncthreads();   // BAR-2: sHB + sX(e+1) visible

        // ---------------- layer 3: oacc += H2 @ W3 (b3f[8] rotating; A lookahead-3) ----------------
        bf16x8 a3f[4][2];
#pragma unroll
        for (int s = 0; s < 3; ++s)
#pragma unroll
            for (int i = 0; i < 2; ++i)
                a3f[s][i] = *(const bf16x8*)&sHB[a3[i] + (((s ^ hi2)) << 5)];

#pragma unroll
        for (int kt = 0; kt < 16; ++kt) {
            const int cur = kt & 3;
            if (kt < 13) {
                const int pre = (kt + 3) & 3;
#pragma unroll
                for (int i = 0; i < 2; ++i)
                    a3f[pre][i] = *(const bf16x8*)&sHB[a3[i] + ((((kt + 3) ^ hi2)) << 5)];
            }
#pragma unroll
            for (int i = 0; i < 2; ++i)
                oacc[i] = __builtin_amdgcn_mfma_f32_16x16x32_bf16(
                    a3f[cur][i], b3f[kt & 7], oacc[i], 0, 0, 0);
            if (kt < 8)    // rotate: slot kt&7 dead after its MFMA; load frag kt+8
                b3f[kt & 7] = *(const bf16x8*)(b3p + (kt + 8) * 512);
        }
        bacc += b3v;
    }

    // final: 4-expert-accumulated contribution -> global fp32 atomics (1 set per block)
#pragma unroll
    for (int i = 0; i < 2; ++i) {
        const int col = n3 * 16 + l16;
#pragma unroll
        for (int r = 0; r < 4; ++r) {
            const int row = b0 + (2 * mp + i) * 16 + q * 4 + r;
            unsafeAtomicAdd(out + (size_t)row * NDO + col, oacc[i][r] + bacc);
        }
    }
}

extern "C" void kernel_launch(void* const* d_in, const int* in_sizes, int n_in,
                              void* d_out, int out_size, void* d_ws, size_t ws_size,
                              hipStream_t stream) {
    const float* x  = (const float*)d_in[0];
    const float* W1 = (const float*)d_in[1];
    const float* b1 = (const float*)d_in[2];
    const float* W2 = (const float*)d_in[3];
    const float* b2 = (const float*)d_in[4];
    const float* W3 = (const float*)d_in[5];
    const float* b3 = (const float*)d_in[6];
    float* out = (float*)d_out;

    unsigned short* W1f = (unsigned short*)d_ws;            // [E*8][4][4][64][8]
    unsigned short* W2f = W1f + (size_t)NE * NH * NDIN;     // [E*8][16][4][64][8]
    unsigned short* W3f = W2f + (size_t)NE * NH * NH;       // [E*4][16][64][8]

    prep_weights<<<dim3(576), 256, 0, stream>>>(W1, W2, W3, W1f, W2f, W3f, out);
    moe_fused<<<dim3((NB / 64) * (NE / EG)), 512, 0, stream>>>(x, b1, b2, b3, W1f, W2f, W3f, out);
}